// Round 1
// 596.290 us; speedup vs baseline: 1.0832x; 1.0832x over previous
//
#include <hip/hip_runtime.h>

// GRU4REC v5: MFMA-based, deep-pipelined embedding gather.
// B=1024, T=256, D=64, H=128. 256 blocks x 512 threads (8 waves), 1 block/CU,
// 4 rows/block (M-pad to 16).
//
// v4 -> v5 changes (theory: latency-bound recurrence, HBM gather stall on
// the critical path):
//  * Embedding gather pipelined 2 steps deep; item_his indices prefetched
//    3 steps ahead (breaks the idx->emb dependent-load chain). Register
//    slots swap by loop parity (no rotate copy), so the vmcnt wait for
//    x_{t+2} lands ~1.7 steps after issue -> ~900-1100 cy HBM latency fully
//    hidden.
//  * Cand x-partial (kt=0,1) moved into phase 1: it reads the same XA
//    A-fragments as the gate (x_t), so phase 2's dependent MFMA chain is
//    4 deep instead of 6 and the phase-1 XC x-commit is eliminated
//    (XC x-region stays zero, never read).
//  * Biases folded into MFMA accumulator init.
// Gate: 12 MFMA + 2 cand-x MFMA in phase 1; cand-rh: 4 MFMA in phase 2.
// 2 barriers/step. Weights persist as B-fragments (18 half8 = 72 VGPR).

#define T_   256
#define D_   64
#define H_   128
#define SROW 208   // halves per A-row (416 B), 16B-aligned

typedef _Float16 half8_t  __attribute__((ext_vector_type(8)));
typedef float    floatx4  __attribute__((ext_vector_type(4)));

__global__ __launch_bounds__(512, 2) void gru_mfma(
    const int* __restrict__ item_his,          // [1024][256]
    const int* __restrict__ seq_lens,          // [1024]
    const float* __restrict__ emb,             // [1e6][64]
    const float* __restrict__ Wg,              // [192][256]
    const float* __restrict__ bg,              // [256]
    const float* __restrict__ Wc,              // [192][128]
    const float* __restrict__ bc,              // [128]
    float* __restrict__ out)                   // [1024][128] fp32
{
    __shared__ __align__(16) _Float16 XA[16][SROW];  // [x | h]     (gate + cand-x A)
    __shared__ __align__(16) _Float16 XC[16][SROW];  // [0 | r*h]   (cand-rh A)

    const int tid  = threadIdx.x;
    const int w    = tid >> 6;        // wave 0..7
    const int lane = tid & 63;
    const int row0 = blockIdx.x * 4;

    // ---- persistent B-fragments ----
    // B-frag (K32xN16): lane holds B[k = kt*32 + (lane>>4)*8 + i][n = lane&15]
    const int bq = lane >> 4;
    const int bn = lane & 15;
    half8_t BG0[6], BG1[6], BC6[6];   // gate-r (nt=w), gate-u (nt=w+8), cand (nt=w)
    #pragma unroll
    for (int kt = 0; kt < 6; ++kt) {
        half8_t f0, f1, fc;
        #pragma unroll
        for (int i = 0; i < 8; ++i) {
            const int k = kt * 32 + bq * 8 + i;
            f0[i] = (_Float16)Wg[k * 256 + (w * 16 + bn)];
            f1[i] = (_Float16)Wg[k * 256 + (128 + w * 16 + bn)];
            fc[i] = (_Float16)Wc[k * 128 + (w * 16 + bn)];
        }
        BG0[kt] = f0; BG1[kt] = f1; BC6[kt] = fc;
    }

    // ---- biases for this wave's columns (col = lane&15) ----
    const float bgR = bg[w * 16 + bn];
    const float bgU = bg[128 + w * 16 + bn];
    const float bcC = bc[w * 16 + bn];

    // ---- sequence lengths ----
    int len[4];
    #pragma unroll
    for (int r = 0; r < 4; ++r) len[r] = seq_lens[row0 + r];
    const int maxlen = max(max(len[0], len[1]), max(len[2], len[3]));

    // ---- zero A-buffers (rows 4..15 stay zero forever; XC x-region too) ----
    {
        unsigned* pa = (unsigned*)&XA[0][0];
        unsigned* pc = (unsigned*)&XC[0][0];
        for (int i = tid; i < 16 * SROW / 2; i += 512) { pa[i] = 0u; pc[i] = 0u; }
    }
    __syncthreads();

    // ---- x-gather mapping: 8 waves x lanes 0..31 cover 4 rows x 64 dims ----
    const int  row_l = w >> 1;
    const int  d_l   = (w & 1) * 32 + (lane & 31);
    const bool ldr   = (lane < 32);
    const int  ibase = (row0 + row_l) * T_;

    // ---- pipeline prologue ----
    // slotA holds x_{t+1} entering step t (t=0 -> x_1); iNow holds idx_{t+2}.
    float xslotA = 0.f, xslotB = 0.f;
    int   iNow = 0, iNew = 0;
    if (ldr) {
        const int i0 = item_his[ibase + 0];
        const int i1 = item_his[ibase + 1];
        iNow = item_his[ibase + 2];                 // idx_2
        const float x0 = emb[(size_t)i0 * D_ + d_l];
        xslotA = emb[(size_t)i1 * D_ + d_l];        // x_1
        XA[row_l][d_l] = (_Float16)x0;              // x_0 committed
    }
    float h[4] = {0.f, 0.f, 0.f, 0.f};
    float u[4] = {0.f, 0.f, 0.f, 0.f};
    __syncthreads();

    // xNow = x_{t+1} (arrived; committed to XA in phase 2)
    // xNew <- x_{t+2} (load issued in phase 1, consumed at step t+1)
    // jNow = idx_{t+2} (feeds this step's emb issue); jNew <- idx_{t+3}
    auto step = [&](int t, float& xNow, float& xNew, int& jNow, int& jNew) {
        // ================= Phase 1: gate + cand-x =================
        if (ldr) {
            xNew = emb[(size_t)jNow * D_ + d_l];                       // x_{t+2}
            const int t3 = (t + 3 < T_) ? (t + 3) : (T_ - 1);
            jNew = item_his[ibase + t3];                               // idx_{t+3}
        }
        floatx4 aR  = {bgR, bgR, bgR, bgR};
        floatx4 aU  = {bgU, bgU, bgU, bgU};
        floatx4 aCx = {bcC, bcC, bcC, bcC};
        #pragma unroll
        for (int kt = 0; kt < 6; ++kt) {
            const half8_t af = *(const half8_t*)&XA[lane & 15][kt * 32 + (lane >> 4) * 8];
            aR = __builtin_amdgcn_mfma_f32_16x16x32_f16(af, BG0[kt], aR, 0, 0, 0);
            aU = __builtin_amdgcn_mfma_f32_16x16x32_f16(af, BG1[kt], aU, 0, 0, 0);
            if (kt < 2)
                aCx = __builtin_amdgcn_mfma_f32_16x16x32_f16(af, BC6[kt], aCx, 0, 0, 0);
        }
        // valid C rows 0..3 live in lanes 0..15 (row = reg, col = lane)
        if (lane < 16) {
            #pragma unroll
            for (int r = 0; r < 4; ++r) {
                const float rg = 1.f / (1.f + __expf(-aR[r]));
                u[r]           = 1.f / (1.f + __expf(-aU[r]));
                XC[r][64 + w * 16 + lane] = (_Float16)(rg * h[r]);     // r * h
            }
        }
        __syncthreads();

        // ================= Phase 2: cand-rh + h update =================
        if (ldr) XA[row_l][d_l] = (_Float16)xNow;   // commit x_{t+1} for next gate
        floatx4 aC = aCx;
        #pragma unroll
        for (int kt = 2; kt < 6; ++kt) {
            const half8_t af = *(const half8_t*)&XC[lane & 15][kt * 32 + (lane >> 4) * 8];
            aC = __builtin_amdgcn_mfma_f32_16x16x32_f16(af, BC6[kt], aC, 0, 0, 0);
        }
        if (lane < 16) {
            #pragma unroll
            for (int r = 0; r < 4; ++r) {
                float s = aC[r];
                s = fminf(fmaxf(s, -15.f), 15.f);
                const float e = __expf(2.f * s);
                const float c = (e - 1.f) / (e + 1.f);          // tanh
                const float hn = u[r] * h[r] + (1.f - u[r]) * c;
                if (t < len[r]) h[r] = hn;                       // copy-through mask
                XA[r][64 + w * 16 + lane] = (_Float16)h[r];
            }
        }
        __syncthreads();
    };

    // parity-unrolled loop: register slots swap roles, no rotate copies,
    // so the wait for x_{t+2} lands at its use ~1.7 steps after issue.
    int t = 0;
    while (t < maxlen) {
        step(t, xslotA, xslotB, iNow, iNew);
        ++t;
        if (t >= maxlen) break;
        step(t, xslotB, xslotA, iNew, iNow);
        ++t;
    }

    // ---- write final h (fp32): wave w covers cols [16w, 16w+16) ----
    if (lane < 16) {
        #pragma unroll
        for (int r = 0; r < 4; ++r)
            out[(row0 + r) * H_ + w * 16 + lane] = h[r];
    }
}

extern "C" void kernel_launch(void* const* d_in, const int* in_sizes, int n_in,
                              void* d_out, int out_size, void* d_ws, size_t ws_size,
                              hipStream_t stream) {
    const int*   item_his = (const int*)d_in[0];
    const int*   seq_lens = (const int*)d_in[1];
    const float* emb      = (const float*)d_in[2];
    const float* Wg       = (const float*)d_in[3];
    const float* bg       = (const float*)d_in[4];
    const float* Wc       = (const float*)d_in[5];
    const float* bc       = (const float*)d_in[6];
    float*       out      = (float*)d_out;

    gru_mfma<<<256, 512, 0, stream>>>(item_his, seq_lens, emb, Wg, bg, Wc, bc, out);
}